// Round 6
// baseline (26.562 us; speedup 1.0000x reference)
//
#include <hip/hip_runtime.h>
#include <math.h>

// Problem constants (from reference setup_inputs)
constexpr int NB = 16;      // batch
constexpr int NA = 3;       // anchors
constexpr int NT = 64;      // targets per image
constexpr int NC = 85;      // channels; pred = channel 4
constexpr int G0 = 64, G1 = 32, G2 = 16;
constexpr int N0 = NB * NA * G0 * G0;   // 196608 cells
constexpr int N1 = NB * NA * G1 * G1;   //  49152
constexpr int N2 = NB * NA * G2 * G2;   //  12288
constexpr int BLK = 256;
constexpr int B0 = N0 / BLK;            // 768 blocks (exact)
constexpr int B1 = N1 / BLK;            // 192
constexpr int B2 = N2 / BLK;            // 48
constexpr int NBLK = B0 + B1 + B2;      // 1008
constexpr double FXSCALE = 67108864.0;  // 2^26 fixed-point scale

// d_out (one float32) doubles as the u32 fixed-point accumulator between
// kernels 1..2, then finalize overwrites it with the float loss. No d_ws use.

__global__ void zero_acc(unsigned int* __restrict__ acc) {
    if (threadIdx.x == 0) acc[0] = 0u;
}

__global__ void obj_loss(const float* __restrict__ o0,
                         const float* __restrict__ o1,
                         const float* __restrict__ o2,
                         const float* __restrict__ an0,
                         const float* __restrict__ an1,
                         const float* __restrict__ an2,
                         const float* __restrict__ targets,
                         unsigned int* __restrict__ acc) {
    int blk = blockIdx.x;
    const float* o; const float* an; int g; int cell0; double w;
    if (blk < B0)           { o = o0; an = an0; g = G0; cell0 = blk * BLK;             w = 1.0 / (double)N0; }
    else if (blk < B0 + B1) { o = o1; an = an1; g = G1; cell0 = (blk - B0) * BLK;      w = 1.0 / (double)N1; }
    else                    { o = o2; an = an2; g = G2; cell0 = (blk - B0 - B1) * BLK; w = 1.0 / (double)N2; }
    int gg = g * g;
    int b = cell0 / (NA * gg);   // per-batch cell counts (12288/3072/768) divide by 256

    __shared__ unsigned int tinfo[NT];
    __shared__ float wsum[BLK / 64];

    // 64 threads: per-target IoU argmax over 3 anchors -> packed cell key
    if (threadIdx.x < NT) {
        const float* tg = targets + (size_t)(b * NT + threadIdx.x) * 5;
        float tx = tg[1], ty = tg[2];
        float tw = tg[3] * (float)g;
        float th = tg[4] * (float)g;
        float best = -1.0f; int ba = 0;
        #pragma unroll
        for (int a = 0; a < NA; ++a) {
            float aw = an[2 * a], ah = an[2 * a + 1];
            float inter = fminf(aw, tw) * fminf(ah, th);
            float uni = aw * ah + tw * th - inter;
            float iou = inter / uni;
            if (iou > best) { best = iou; ba = a; }  // strict >: first-wins ties == jnp.argmax
        }
        unsigned int info = 0u;
        if (best > 0.5f) {
            int ti = (int)floorf(tx * (float)g);   // tx in [0,1) -> ti in [0,g-1], no clamp needed
            int tj = (int)floorf(ty * (float)g);
            ti = min(max(ti, 0), g - 1);
            tj = min(max(tj, 0), g - 1);
            info = 0x80000000u | ((unsigned)ba << 20) | ((unsigned)tj << 10) | (unsigned)ti;
        }
        tinfo[threadIdx.x] = info;
    }
    __syncthreads();

    // each thread: does any target mark my cell?
    int cell = cell0 + (int)threadIdx.x;
    int a_c = (cell / gg) % NA;
    int rem = cell % gg;
    unsigned int key = 0x80000000u | ((unsigned)a_c << 20)
                     | ((unsigned)(rem / g) << 10) | (unsigned)(rem % g);
    bool hit = false;
    #pragma unroll 8
    for (int t = 0; t < NT; ++t) hit |= (tinfo[t] == key);

    float pred = o[(size_t)cell * NC + 4];
    float p = fminf(fmaxf(pred, 1e-7f), 1.0f - 1e-7f);
    float term = hit ? (-logf(p)) : (-log1pf(-p));

    // wave64 shuffle reduce, then cross-wave via LDS
    #pragma unroll
    for (int off = 32; off > 0; off >>= 1)
        term += __shfl_down(term, off);
    int lane = threadIdx.x & 63, wv = threadIdx.x >> 6;
    if (lane == 0) wsum[wv] = term;
    __syncthreads();
    if (threadIdx.x == 0) {
        double s = (double)wsum[0] + (double)wsum[1] + (double)wsum[2] + (double)wsum[3];
        // weighted block partial in 2^26 fixed point; integer atomics => exact determinism
        unsigned int q = (unsigned int)(s * w * FXSCALE + 0.5);
        atomicAdd(acc, q);
    }
}

__global__ void finalize_out(float* __restrict__ out) {
    if (threadIdx.x == 0) {
        unsigned int v = *(volatile unsigned int*)out;  // fixed-point accumulator
        out[0] = (float)((double)v / FXSCALE);          // overwrite with float32 loss
    }
}

extern "C" void kernel_launch(void* const* d_in, const int* in_sizes, int n_in,
                              void* d_out, int out_size, void* d_ws, size_t ws_size,
                              hipStream_t stream) {
    // setup_inputs() dict order is INTERLEAVED: out0, anchors0, out1, anchors1,
    // out2, anchors2, targets. Guard on in_sizes (deterministic) just in case.
    const float *o0, *o1, *o2, *an0, *an1, *an2, *targets;
    if (in_sizes[1] == 6) {           // interleaved (expected)
        o0  = (const float*)d_in[0];  an0 = (const float*)d_in[1];
        o1  = (const float*)d_in[2];  an1 = (const float*)d_in[3];
        o2  = (const float*)d_in[4];  an2 = (const float*)d_in[5];
    } else {                          // grouped fallback
        o0  = (const float*)d_in[0];  o1  = (const float*)d_in[1];
        o2  = (const float*)d_in[2];  an0 = (const float*)d_in[3];
        an1 = (const float*)d_in[4];  an2 = (const float*)d_in[5];
    }
    targets = (const float*)d_in[6];

    unsigned int* acc = (unsigned int*)d_out;

    zero_acc<<<1, 64, 0, stream>>>(acc);
    obj_loss<<<NBLK, BLK, 0, stream>>>(o0, o1, o2, an0, an1, an2, targets, acc);
    finalize_out<<<1, 64, 0, stream>>>((float*)d_out);
}

// Round 7
// 11.716 us; speedup vs baseline: 2.2672x; 2.2672x over previous
//
#include <hip/hip_runtime.h>
#include <math.h>

// Problem constants (from reference setup_inputs)
constexpr int NB = 16;      // batch
constexpr int NA = 3;       // anchors
constexpr int NT = 64;      // targets per image
constexpr int NC = 85;      // channels; pred = channel 4
constexpr int G0 = 64, G1 = 32, G2 = 16;
constexpr int N0 = NB * NA * G0 * G0;   // 196608
constexpr int N1 = NB * NA * G1 * G1;   //  49152
constexpr int N2 = NB * NA * G2 * G2;   //  12288
constexpr int BLK = 256;
// one block per (batch, chunk): scale0 12 chunks x 1024, scale1 3 x 1024, scale2 1 x 768
constexpr int NBLK0 = NB * 12;          // 192
constexpr int NBLK1 = NB * 3;           //  48
constexpr int NBLK2 = NB;               //  16
constexpr int NBLK  = NBLK0 + NBLK1 + NBLK2;  // 256 (== finalize block size)

// Per (batch,scale): build gt bitmask in LDS from <=64 targets, then bit-test
// each cell. G compile-time -> divisions become shifts.
template<int G, int NITER>
__device__ __forceinline__ float scale_sum(const float* __restrict__ o,
                                           const float* __restrict__ an,
                                           const float* __restrict__ targets,
                                           int b, int cell0,
                                           unsigned int* __restrict__ mask) {
    constexpr int GG = G * G;
    constexpr int NWORDS = NA * GG / 32;
    const int tid = threadIdx.x;

    for (int k = tid; k < NWORDS; k += BLK) mask[k] = 0u;
    __syncthreads();

    if (tid < NT) {
        const float* tg = targets + (size_t)(b * NT + tid) * 5;
        float tx = tg[1], ty = tg[2];
        float tw = tg[3] * (float)G;
        float th = tg[4] * (float)G;
        float best = -1.0f; int ba = 0;
        #pragma unroll
        for (int a = 0; a < NA; ++a) {
            float aw = an[2 * a], ah = an[2 * a + 1];
            float inter = fminf(aw, tw) * fminf(ah, th);
            float uni = aw * ah + tw * th - inter;
            float iou = inter / uni;
            if (iou > best) { best = iou; ba = a; }  // strict >: first-wins == jnp.argmax
        }
        if (best > 0.5f) {
            int ti = min(max((int)floorf(tx * (float)G), 0), G - 1);
            int tj = min(max((int)floorf(ty * (float)G), 0), G - 1);
            int cell = (ba * G + tj) * G + ti;       // within this batch's scale grid
            atomicOr(&mask[cell >> 5], 1u << (cell & 31));
        }
    }
    __syncthreads();

    float sum = 0.0f;
    #pragma unroll
    for (int k = 0; k < NITER; ++k) {
        int cl = cell0 + k * BLK + tid;              // cell within batch grid
        float pred = o[(size_t)(b * (NA * GG) + cl) * NC + 4];
        float p = fminf(fmaxf(pred, 1e-7f), 1.0f - 1e-7f);
        unsigned int bit = (mask[cl >> 5] >> (cl & 31)) & 1u;
        sum += bit ? (-logf(p)) : (-log1pf(-p));
    }
    return sum;
}

__global__ __launch_bounds__(BLK) void obj_loss(const float* __restrict__ o0,
                                                const float* __restrict__ o1,
                                                const float* __restrict__ o2,
                                                const float* __restrict__ an0,
                                                const float* __restrict__ an1,
                                                const float* __restrict__ an2,
                                                const float* __restrict__ targets,
                                                double* __restrict__ partials) {
    __shared__ unsigned int mask[NA * G0 * G0 / 32];   // 384 words (max of 3 scales)
    __shared__ double wsum[BLK / 64];
    const int blk = blockIdx.x;
    const int tid = threadIdx.x;

    float s; double w;
    if (blk < NBLK0) {
        int b = blk / 12, c = blk % 12;
        s = scale_sum<G0, 4>(o0, an0, targets, b, c * 1024, mask);
        w = 1.0 / (double)N0;
    } else if (blk < NBLK0 + NBLK1) {
        int r = blk - NBLK0; int b = r / 3, c = r % 3;
        s = scale_sum<G1, 4>(o1, an1, targets, b, c * 1024, mask);
        w = 1.0 / (double)N1;
    } else {
        int b = blk - NBLK0 - NBLK1;
        s = scale_sum<G2, 3>(o2, an2, targets, b, 0, mask);
        w = 1.0 / (double)N2;
    }

    // wave64 shuffle reduce in double, then cross-wave via LDS
    double acc = (double)s;
    #pragma unroll
    for (int off = 32; off > 0; off >>= 1)
        acc += __shfl_down(acc, off);
    const int lane = tid & 63, wv = tid >> 6;
    if (lane == 0) wsum[wv] = acc;
    __syncthreads();
    if (tid == 0) {
        double t = wsum[0] + wsum[1] + wsum[2] + wsum[3];
        partials[blk] = t * w;   // every slot written every call -> poison-safe
    }
}

__global__ __launch_bounds__(NBLK) void finalize(const double* __restrict__ partials,
                                                 float* __restrict__ out) {
    __shared__ double sm[NBLK];
    const int tid = threadIdx.x;
    sm[tid] = partials[tid];
    __syncthreads();
    #pragma unroll
    for (int off = NBLK / 2; off > 0; off >>= 1) {
        if (tid < off) sm[tid] += sm[tid + off];
        __syncthreads();
    }
    if (tid == 0) out[0] = (float)sm[0];
}

extern "C" void kernel_launch(void* const* d_in, const int* in_sizes, int n_in,
                              void* d_out, int out_size, void* d_ws, size_t ws_size,
                              hipStream_t stream) {
    // setup_inputs() dict order is INTERLEAVED: out0, anchors0, out1, anchors1,
    // out2, anchors2, targets. Guard on in_sizes (deterministic) just in case.
    const float *o0, *o1, *o2, *an0, *an1, *an2, *targets;
    if (in_sizes[1] == 6) {           // interleaved (expected)
        o0  = (const float*)d_in[0];  an0 = (const float*)d_in[1];
        o1  = (const float*)d_in[2];  an1 = (const float*)d_in[3];
        o2  = (const float*)d_in[4];  an2 = (const float*)d_in[5];
    } else {                          // grouped fallback
        o0  = (const float*)d_in[0];  o1  = (const float*)d_in[1];
        o2  = (const float*)d_in[2];  an0 = (const float*)d_in[3];
        an1 = (const float*)d_in[4];  an2 = (const float*)d_in[5];
    }
    targets = (const float*)d_in[6];

    double* partials = (double*)d_ws;   // 256 * 8 B = 2 KB

    obj_loss<<<NBLK, BLK, 0, stream>>>(o0, o1, o2, an0, an1, an2, targets, partials);
    finalize<<<1, NBLK, 0, stream>>>(partials, (float*)d_out);
}